// Round 1
// baseline (521.083 us; speedup 1.0000x reference)
//
#include <hip/hip_runtime.h>
#include <math.h>

#define HH 512
#define WW 512
#define NIMG 24
#define CCH 3
#define TAU 0.25f
#define TVEPS 2e-4f
#define NUMEL 262144.0f
#define TILE 64
#define NITER 10

// Scalars layout in ws (floats):
// [0..23]   sum_dt2
// [24..47]  sum_norm
// [48..71]  E_prev
// [72..95]  E_init
// [96..119] done (int, viewed through cast)

__global__ __launch_bounds__(256) void tv_step(
    const float* __restrict__ img, const float* __restrict__ weight,
    float* __restrict__ out, const float* __restrict__ pt_in,
    float* __restrict__ pt_out, float* __restrict__ sc, int it)
{
    const int im = blockIdx.z;
    if (it > 0) {
        if (((const int*)sc)[96 + im]) return;  // frozen (converged earlier)
    }
    const float w = weight[im / CCH];
    const int x0 = blockIdx.x * TILE;
    const int y0 = blockIdx.y * TILE;
    const size_t ioff = (size_t)im * HH * WW;
    const float* imgI = img + ioff;
    float* outI = out + ioff;
    const float* p0in = pt_in + (size_t)im * 2 * HH * WW;
    const float* p1in = p0in + HH * WW;
    float* p0out = pt_out + (size_t)im * 2 * HH * WW;
    float* p1out = p0out + HH * WW;

    __shared__ float s_out[TILE + 1][TILE + 2];  // +2 pad on inner dim
    const int tid = threadIdx.x;

    // Pass 1: out_new on extended region (TILE+1)x(TILE+1)
    for (int idx = tid; idx < (TILE + 1) * (TILE + 1); idx += 256) {
        int ey = idx / (TILE + 1);
        int ex = idx - ey * (TILE + 1);
        int gy = y0 + ey, gx = x0 + ex;
        if (gy < HH && gx < WW) {
            float o;
            if (it == 0) {
                o = imgI[gy * WW + gx];
            } else {
                float dt = -(p0in[gy * WW + gx] + p1in[gy * WW + gx]);
                if (gy > 0) dt += p0in[(gy - 1) * WW + gx];
                if (gx > 0) dt += p1in[gy * WW + gx - 1];
                o = imgI[gy * WW + gx] + dt;
            }
            s_out[ey][ex] = o;
        }
    }
    __syncthreads();

    // Pass 2: main region — gradients, norm, pt update, accumulations
    float acc_dt2 = 0.f, acc_nrm = 0.f;
    const float tau_w = TAU / w;
    for (int idx = tid; idx < TILE * TILE; idx += 256) {
        int ey = idx >> 6;  // TILE == 64
        int ex = idx & 63;
        int gy = y0 + ey, gx = x0 + ex;
        float o = s_out[ey][ex];
        float g0 = (gy < HH - 1) ? (s_out[ey + 1][ex] - o) : 0.f;
        float g1 = (gx < WW - 1) ? (s_out[ey][ex + 1] - o) : 0.f;
        float s = g0 * g0 + g1 * g1;
        float nrm = (s > 0.f) ? sqrtf(s) : 0.f;
        acc_nrm += nrm;
        float inv = 1.0f / (1.0f + tau_w * nrm);
        float p0o = 0.f, p1o = 0.f;
        if (it > 0) {
            p0o = p0in[gy * WW + gx];
            p1o = p1in[gy * WW + gx];
            float dt = o - imgI[gy * WW + gx];
            acc_dt2 += dt * dt;
        }
        p0out[gy * WW + gx] = (p0o - TAU * g0) * inv;
        p1out[gy * WW + gx] = (p1o - TAU * g1) * inv;
        outI[gy * WW + gx] = o;
    }

    // Block reduction: wave shuffle (64-lane) then cross-wave via LDS
    for (int off = 32; off > 0; off >>= 1) {
        acc_dt2 += __shfl_down(acc_dt2, off, 64);
        acc_nrm += __shfl_down(acc_nrm, off, 64);
    }
    __shared__ float s_red[2][4];
    int wave = tid >> 6, lane = tid & 63;
    if (lane == 0) { s_red[0][wave] = acc_dt2; s_red[1][wave] = acc_nrm; }
    __syncthreads();
    if (tid == 0) {
        float d2 = s_red[0][0] + s_red[0][1] + s_red[0][2] + s_red[0][3];
        float nr = s_red[1][0] + s_red[1][1] + s_red[1][2] + s_red[1][3];
        if (it > 0) atomicAdd(&sc[im], d2);
        atomicAdd(&sc[24 + im], nr);
    }
}

__global__ void tv_finalize(const float* __restrict__ weight,
                            float* __restrict__ sc, int it)
{
    int im = threadIdx.x;
    if (im >= NIMG) return;
    int* done = (int*)(sc + 96);
    if (it == 0) {
        float E = weight[im / CCH] * sc[24 + im] / NUMEL;
        sc[48 + im] = E;  // E_prev
        sc[72 + im] = E;  // E_init
        done[im] = 0;
    } else if (!done[im]) {
        float Et = (sc[im] + weight[im / CCH] * sc[24 + im]) / NUMEL;
        if (fabsf(sc[48 + im] - Et) < TVEPS * sc[72 + im]) done[im] = 1;
        sc[48 + im] = Et;  // E_prev = Et (update happens even on the converging iter)
    }
    sc[im] = 0.f;       // reset accumulators for next iteration
    sc[24 + im] = 0.f;
}

extern "C" void kernel_launch(void* const* d_in, const int* in_sizes, int n_in,
                              void* d_out, int out_size, void* d_ws, size_t ws_size,
                              hipStream_t stream)
{
    const float* img = (const float*)d_in[0];
    const float* weight = (const float*)d_in[1];
    float* out = (float*)d_out;
    float* sc = (float*)d_ws;
    float* ptA = (float*)((char*)d_ws + 1024);
    float* ptB = ptA + (size_t)2 * NIMG * HH * WW;  // 48 MB apart

    hipMemsetAsync(d_ws, 0, 1024, stream);  // zero accumulators + done flags

    dim3 grid(WW / TILE, HH / TILE, NIMG);
    dim3 block(256);

    // Iteration 0: pt starts implicitly at zero (not read), writes ptA
    tv_step<<<grid, block, 0, stream>>>(img, weight, out, ptB, ptA, sc, 0);
    tv_finalize<<<1, 64, 0, stream>>>(weight, sc, 0);

    for (int it = 1; it < NITER; ++it) {
        float* pin  = (it & 1) ? ptA : ptB;
        float* pout = (it & 1) ? ptB : ptA;
        tv_step<<<grid, block, 0, stream>>>(img, weight, out, pin, pout, sc, it);
        if (it < NITER - 1)
            tv_finalize<<<1, 64, 0, stream>>>(weight, sc, it);
    }
}

// Round 3
// 393.770 us; speedup vs baseline: 1.3233x; 1.3233x over previous
//
#include <hip/hip_runtime.h>
#include <hip/hip_fp16.h>
#include <math.h>

#define HH 512
#define WW 512
#define NIMG 24
#define CCH 3
#define TAU 0.25f
#define TVEPS 2e-4f
#define NUMEL 262144.0f
#define TILE 64
#define NITER 10

// ws layout:
// sc floats [0..143]: [48..71] E_prev, [72..95] E_init,
//                     int view [96..119] done, [120..143] last_k
// byte 2048 : pd partials (24*64 floats)
// byte 8192 : pn partials (24*64 floats)
// byte 16384: imgh (__half, 24*512*512 = 12.58 MB)
// byte 12599296: ptA (__half2 packed, 25.17 MB)
// byte 37765120: ptB (__half2 packed, 25.17 MB)

__device__ __forceinline__ void block_reduce_store(float v0, float v1,
                                                   float* p0, float* p1, int tid) {
    for (int off = 32; off > 0; off >>= 1) {
        v0 += __shfl_down(v0, off, 64);
        v1 += __shfl_down(v1, off, 64);
    }
    __shared__ float sr[2][4];
    int wave = tid >> 6, lane = tid & 63;
    if (lane == 0) { sr[0][wave] = v0; sr[1][wave] = v1; }
    __syncthreads();
    if (tid == 0) {
        *p0 = (sr[0][0] + sr[0][1]) + (sr[0][2] + sr[0][3]);
        *p1 = (sr[1][0] + sr[1][1]) + (sr[1][2] + sr[1][3]);
    }
}

// Iteration 0: out_new = img. Gradients, norm partials, first pt, fp16 img copy.
__global__ __launch_bounds__(256) void tv_step0(
    const float* __restrict__ img, const float* __restrict__ weight,
    __half* __restrict__ imgh, __half2* __restrict__ ptout,
    float* __restrict__ pd, float* __restrict__ pn)
{
    const int im = blockIdx.z;
    const int bid = blockIdx.y * 8 + blockIdx.x;
    const float w = weight[im / CCH];
    const int x0 = blockIdx.x * TILE, y0 = blockIdx.y * TILE;
    const float* imgI = img + (size_t)im * HH * WW;
    __half* hI = imgh + (size_t)im * HH * WW;
    __half2* pI = ptout + (size_t)im * HH * WW;
    __shared__ float s[TILE + 1][TILE + 2];
    const int tid = threadIdx.x;

    for (int idx = tid; idx < (TILE + 1) * (TILE + 1); idx += 256) {
        int ey = idx / (TILE + 1), ex = idx - ey * (TILE + 1);
        int gy = y0 + ey, gx = x0 + ex;
        if (gy < HH && gx < WW) s[ey][ex] = imgI[gy * WW + gx];
    }
    __syncthreads();

    float accn = 0.f;
    const float tw = TAU / w;
    for (int idx = tid; idx < TILE * TILE; idx += 256) {
        int ey = idx >> 6, ex = idx & 63;
        int gy = y0 + ey, gx = x0 + ex;
        float o = s[ey][ex];
        float g0 = (gy < HH - 1) ? (s[ey + 1][ex] - o) : 0.f;
        float g1 = (gx < WW - 1) ? (s[ey][ex + 1] - o) : 0.f;
        float ss = g0 * g0 + g1 * g1;
        float nrm = (ss > 0.f) ? sqrtf(ss) : 0.f;
        accn += nrm;
        float inv = 1.f / (1.f + tw * nrm);
        pI[gy * WW + gx] = __floats2half2_rn(-TAU * g0 * inv, -TAU * g1 * inv);
        hI[gy * WW + gx] = __float2half(o);
    }
    block_reduce_store(0.f, accn, &pd[im * 64 + bid], &pn[im * 64 + bid], tid);
}

// Iterations 1..9: out_new = imgh + div(pt_in); update pt; partial sums.
__global__ __launch_bounds__(256) void tv_stepN(
    const __half* __restrict__ imgh, const float* __restrict__ weight,
    const __half2* __restrict__ pt_in, __half2* __restrict__ pt_out,
    const float* __restrict__ sc, float* __restrict__ pd, float* __restrict__ pn)
{
    const int im = blockIdx.z;
    if (((const int*)sc)[96 + im]) return;  // frozen
    const int bid = blockIdx.y * 8 + blockIdx.x;
    const float w = weight[im / CCH];
    const int x0 = blockIdx.x * TILE, y0 = blockIdx.y * TILE;
    const __half* hI = imgh + (size_t)im * HH * WW;
    const __half2* pinI = pt_in + (size_t)im * HH * WW;
    __half2* poutI = pt_out + (size_t)im * HH * WW;
    __shared__ float s[TILE + 1][TILE + 2];
    const int tid = threadIdx.x;

    for (int idx = tid; idx < (TILE + 1) * (TILE + 1); idx += 256) {
        int ey = idx / (TILE + 1), ex = idx - ey * (TILE + 1);
        int gy = y0 + ey, gx = x0 + ex;
        if (gy < HH && gx < WW) {
            __half2 c = pinI[gy * WW + gx];
            float dt = -(__low2float(c) + __high2float(c));
            if (gy > 0) dt += __low2float(pinI[(gy - 1) * WW + gx]);
            if (gx > 0) dt += __high2float(pinI[gy * WW + gx - 1]);
            s[ey][ex] = __half2float(hI[gy * WW + gx]) + dt;
        }
    }
    __syncthreads();

    float accd = 0.f, accn = 0.f;
    const float tw = TAU / w;
    for (int idx = tid; idx < TILE * TILE; idx += 256) {
        int ey = idx >> 6, ex = idx & 63;
        int gy = y0 + ey, gx = x0 + ex;
        float o = s[ey][ex];
        float g0 = (gy < HH - 1) ? (s[ey + 1][ex] - o) : 0.f;
        float g1 = (gx < WW - 1) ? (s[ey][ex + 1] - o) : 0.f;
        float ss = g0 * g0 + g1 * g1;
        float nrm = (ss > 0.f) ? sqrtf(ss) : 0.f;
        accn += nrm;
        float dt = o - __half2float(hI[gy * WW + gx]);
        accd += dt * dt;
        __half2 c = pinI[gy * WW + gx];  // L1-hot reload
        float inv = 1.f / (1.f + tw * nrm);
        poutI[gy * WW + gx] = __floats2half2_rn((__low2float(c) - TAU * g0) * inv,
                                                (__high2float(c) - TAU * g1) * inv);
    }
    block_reduce_store(accd, accn, &pd[im * 64 + bid], &pn[im * 64 + bid], tid);
}

// Deterministic per-image reduction + convergence bookkeeping.
// grid = 24 blocks, 64 threads. Fixed shuffle-tree order -> bit-reproducible.
__global__ void tv_reduce_fin(const float* __restrict__ weight,
                              float* __restrict__ sc,
                              const float* __restrict__ pd,
                              const float* __restrict__ pn, int it)
{
    const int im = blockIdx.x;
    int* done = (int*)(sc + 96);
    int* last_k = (int*)(sc + 120);
    if (it > 0 && done[im]) return;
    const int lane = threadIdx.x;
    float d = (it > 0) ? pd[im * 64 + lane] : 0.f;
    float n = pn[im * 64 + lane];
    for (int off = 32; off > 0; off >>= 1) {
        d += __shfl_down(d, off, 64);
        n += __shfl_down(n, off, 64);
    }
    if (lane == 0) {
        float w = weight[im / CCH];
        if (it == 0) {
            float E = w * n / NUMEL;
            sc[48 + im] = E;   // E_prev
            sc[72 + im] = E;   // E_init
            done[im] = 0;
            last_k[im] = 0;
        } else {
            last_k[im] = it;
            float Et = (d + w * n) / NUMEL;
            if (fabsf(sc[48 + im] - Et) < TVEPS * sc[72 + im]) done[im] = 1;
            sc[48 + im] = Et;
        }
    }
}

// Epilogue: out = img(fp32) + div(pt input of each image's last executed step).
__global__ __launch_bounds__(256) void tv_out(
    const float* __restrict__ img, float* __restrict__ out,
    const __half2* __restrict__ ptA, const __half2* __restrict__ ptB,
    const float* __restrict__ sc)
{
    const int im = blockIdx.z;
    const int* si = (const int*)sc;
    int k = si[96 + im] ? si[120 + im] : (NITER - 1);   // last executed step
    const __half2* p = ((((k - 1) & 1) == 0) ? ptA : ptB) + (size_t)im * HH * WW;
    const float* imgI = img + (size_t)im * HH * WW;
    float* outI = out + (size_t)im * HH * WW;
    const int x0 = blockIdx.x * TILE, y0 = blockIdx.y * TILE;
    const int tid = threadIdx.x;
    for (int idx = tid; idx < TILE * TILE; idx += 256) {
        int ey = idx >> 6, ex = idx & 63;
        int gy = y0 + ey, gx = x0 + ex;
        __half2 c = p[gy * WW + gx];
        float dt = -(__low2float(c) + __high2float(c));
        if (gy > 0) dt += __low2float(p[(gy - 1) * WW + gx]);
        if (gx > 0) dt += __high2float(p[gy * WW + gx - 1]);
        outI[gy * WW + gx] = imgI[gy * WW + gx] + dt;
    }
}

extern "C" void kernel_launch(void* const* d_in, const int* in_sizes, int n_in,
                              void* d_out, int out_size, void* d_ws, size_t ws_size,
                              hipStream_t stream)
{
    const float* img = (const float*)d_in[0];
    const float* weight = (const float*)d_in[1];
    float* out = (float*)d_out;
    float* sc = (float*)d_ws;
    float* pd = (float*)((char*)d_ws + 2048);
    float* pn = (float*)((char*)d_ws + 8192);
    __half* imgh = (__half*)((char*)d_ws + 16384);
    __half2* ptA = (__half2*)((char*)d_ws + 12599296);
    __half2* ptB = (__half2*)((char*)d_ws + 37765120);

    dim3 grid(WW / TILE, HH / TILE, NIMG);
    dim3 block(256);

    tv_step0<<<grid, block, 0, stream>>>(img, weight, imgh, ptA, pd, pn);
    tv_reduce_fin<<<NIMG, 64, 0, stream>>>(weight, sc, pd, pn, 0);

    for (int it = 1; it < NITER; ++it) {
        __half2* pin  = (((it - 1) & 1) == 0) ? ptA : ptB;
        __half2* pout = ((it & 1) == 0) ? ptA : ptB;
        tv_stepN<<<grid, block, 0, stream>>>(imgh, weight, pin, pout, sc, pd, pn);
        if (it < NITER - 1)
            tv_reduce_fin<<<NIMG, 64, 0, stream>>>(weight, sc, pd, pn, it);
    }
    tv_out<<<grid, block, 0, stream>>>(img, out, ptA, ptB, sc);
}

// Round 4
// 286.160 us; speedup vs baseline: 1.8209x; 1.3760x over previous
//
#include <hip/hip_runtime.h>
#include <hip/hip_fp16.h>
#include <math.h>
#include <stdint.h>

#define HH 512
#define WW 512
#define NIMG 24
#define CCH 3
#define TAU 0.25f
#define TVEPS 2e-4f
#define NUMEL 262144.0f
#define NITER 10

// ws layout:
// sc floats: [48..71] E_prev, [72..95] E_init; int view [96..119] done, [120..143] last_k
// byte 2048 : pd partials (24*64 floats)
// byte 8192 : pn partials (24*64 floats)
// byte 16384: imgh (__half, 24*512*512)
// byte 12599296: ptA (uint32 packed half2)
// byte 37765120: ptB

__device__ __forceinline__ float2 h2f(uint32_t v) {
    __half2 h; *reinterpret_cast<uint32_t*>(&h) = v;
    return __half22float2(h);
}
__device__ __forceinline__ uint32_t f2h2(float a, float b) {
    __half2 h = __floats2half2_rn(a, b);
    return *reinterpret_cast<uint32_t*>(&h);
}
__device__ __forceinline__ void h4_to_f(uint2 hv, float* f) {
    float2 a = h2f(hv.x), b = h2f(hv.y);
    f[0] = a.x; f[1] = a.y; f[2] = b.x; f[3] = b.y;
}

__device__ __forceinline__ void block_reduce_store(float v0, float v1,
                                                   float* p0, float* p1, int tid) {
    for (int off = 32; off > 0; off >>= 1) {
        v0 += __shfl_down(v0, off, 64);
        v1 += __shfl_down(v1, off, 64);
    }
    __shared__ float sr[2][4];
    int wave = tid >> 6, lane = tid & 63;
    if (lane == 0) { sr[0][wave] = v0; sr[1][wave] = v1; }
    __syncthreads();
    if (tid == 0) {
        *p0 = (sr[0][0] + sr[0][1]) + (sr[0][2] + sr[0][3]);
        *p1 = (sr[1][0] + sr[1][1]) + (sr[1][2] + sr[1][3]);
    }
}

// Iteration 0: out = img. 4px-wide strips, all global I/O 16B.
__global__ __launch_bounds__(256, 4) void tv_step0(
    const float* __restrict__ img, const float* __restrict__ weight,
    __half* __restrict__ imgh, uint32_t* __restrict__ ptout,
    float* __restrict__ pd, float* __restrict__ pn)
{
    const int im = blockIdx.z;
    const int bid = blockIdx.y * 8 + blockIdx.x;
    const float w = weight[im / CCH];
    const int x0 = blockIdx.x * 64, y0 = blockIdx.y * 64;
    const float* imgI = img + (size_t)im * HH * WW;
    __half* hI = imgh + (size_t)im * HH * WW;
    uint32_t* pI = ptout + (size_t)im * HH * WW;
    __shared__ float s[65][68];
    const int tid = threadIdx.x;
    const int tx = tid & 15, ry = tid >> 4;
    const int gx = x0 + 4 * tx;

    float o[4][4];
    #pragma unroll
    for (int i = 0; i < 4; ++i) {
        int ey = ry + 16 * i, gy = y0 + ey;
        float4 v = *(const float4*)(imgI + (size_t)gy * WW + gx);
        o[i][0] = v.x; o[i][1] = v.y; o[i][2] = v.z; o[i][3] = v.w;
        *(float4*)&s[ey][4 * tx] = v;
    }
    if (tx == 15 && x0 + 64 < WW) {
        #pragma unroll
        for (int i = 0; i < 4; ++i) {
            int ey = ry + 16 * i, gy = y0 + ey;
            s[ey][64] = imgI[(size_t)gy * WW + x0 + 64];
        }
    }
    if (ry == 0 && y0 + 64 < HH) {
        *(float4*)&s[64][4 * tx] = *(const float4*)(imgI + (size_t)(y0 + 64) * WW + gx);
    }
    __syncthreads();

    float accn = 0.f;
    const float tw = TAU / w;
    #pragma unroll
    for (int i = 0; i < 4; ++i) {
        int ey = ry + 16 * i, gy = y0 + ey;
        float4 dn = *(float4*)&s[ey + 1][4 * tx];
        float rt_sh = __shfl_down(o[i][0], 1, 64);
        float rt = (tx == 15) ? s[ey][64] : rt_sh;
        float dnv[4] = {dn.x, dn.y, dn.z, dn.w};
        uint32_t pv[4];
        #pragma unroll
        for (int j = 0; j < 4; ++j) {
            float ov = o[i][j];
            float g0 = (gy < HH - 1) ? dnv[j] - ov : 0.f;
            float rn = (j < 3) ? o[i][j + 1] : rt;
            float g1 = (gx + j < WW - 1) ? rn - ov : 0.f;
            float ss2 = g0 * g0 + g1 * g1;
            float nrm = (ss2 > 0.f) ? sqrtf(ss2) : 0.f;
            accn += nrm;
            float inv = 1.f / (1.f + tw * nrm);
            pv[j] = f2h2(-TAU * g0 * inv, -TAU * g1 * inv);
        }
        size_t off = (size_t)gy * WW + gx;
        *(uint4*)(pI + off) = make_uint4(pv[0], pv[1], pv[2], pv[3]);
        *(uint2*)(hI + off) = make_uint2(f2h2(o[i][0], o[i][1]), f2h2(o[i][2], o[i][3]));
    }
    block_reduce_store(0.f, accn, &pd[im * 64 + bid], &pn[im * 64 + bid], tid);
}

// Iterations 1..9.
__global__ __launch_bounds__(256, 4) void tv_stepN(
    const __half* __restrict__ imgh, const float* __restrict__ weight,
    const uint32_t* __restrict__ pt_in, uint32_t* __restrict__ pt_out,
    const float* __restrict__ sc, float* __restrict__ pd, float* __restrict__ pn)
{
    const int im = blockIdx.z;
    if (((const int*)sc)[96 + im]) return;  // frozen
    const int bid = blockIdx.y * 8 + blockIdx.x;
    const float w = weight[im / CCH];
    const int x0 = blockIdx.x * 64, y0 = blockIdx.y * 64;
    const __half* hI = imgh + (size_t)im * HH * WW;
    const uint32_t* pinI = pt_in + (size_t)im * HH * WW;
    uint32_t* poutI = pt_out + (size_t)im * HH * WW;
    __shared__ float s[65][68];
    const int tid = threadIdx.x;
    const int tx = tid & 15, ry = tid >> 4;
    const int gx = x0 + 4 * tx;

    uint32_t c[4][4];
    float o[4][4], im4[4][4];

    #pragma unroll
    for (int i = 0; i < 4; ++i) {
        int ey = ry + 16 * i, gy = y0 + ey;
        size_t off = (size_t)gy * WW + gx;
        uint4 cv = *(const uint4*)(pinI + off);
        uint4 uv = make_uint4(0u, 0u, 0u, 0u);
        if (gy > 0) uv = *(const uint4*)(pinI + off - WW);
        uint32_t lf = (gx > 0) ? pinI[off - 1] : 0u;
        uint2 hv = *(const uint2*)(hI + off);
        float imv[4]; h4_to_f(hv, imv);
        c[i][0] = cv.x; c[i][1] = cv.y; c[i][2] = cv.z; c[i][3] = cv.w;
        uint32_t uu[4] = {uv.x, uv.y, uv.z, uv.w};
        uint32_t lt[4] = {lf, cv.x, cv.y, cv.z};
        #pragma unroll
        for (int j = 0; j < 4; ++j) {
            float2 cf = h2f(c[i][j]);
            float dt = -(cf.x + cf.y) + h2f(uu[j]).x + h2f(lt[j]).y;
            o[i][j] = imv[j] + dt;
            im4[i][j] = imv[j];
        }
        *(float4*)&s[ey][4 * tx] = make_float4(o[i][0], o[i][1], o[i][2], o[i][3]);
    }
    if (tx == 15 && x0 + 64 < WW) {
        #pragma unroll
        for (int i = 0; i < 4; ++i) {
            int ey = ry + 16 * i, gy = y0 + ey;
            size_t off = (size_t)gy * WW + x0 + 64;
            uint32_t c2 = pinI[off];
            uint32_t u2 = (gy > 0) ? pinI[off - WW] : 0u;
            float2 cf = h2f(c2);
            float dt = -(cf.x + cf.y) + h2f(u2).x + h2f(c[i][3]).y;
            s[ey][64] = __half2float(hI[off]) + dt;
        }
    }
    if (ry == 0 && y0 + 64 < HH) {
        int gy = y0 + 64;
        size_t off = (size_t)gy * WW + gx;
        uint4 cv = *(const uint4*)(pinI + off);
        uint4 uv = *(const uint4*)(pinI + off - WW);
        uint32_t lf = (gx > 0) ? pinI[off - 1] : 0u;
        uint2 hv = *(const uint2*)(hI + off);
        float imv[4]; h4_to_f(hv, imv);
        uint32_t cc[4] = {cv.x, cv.y, cv.z, cv.w};
        uint32_t uu[4] = {uv.x, uv.y, uv.z, uv.w};
        uint32_t lt[4] = {lf, cv.x, cv.y, cv.z};
        float ob[4];
        #pragma unroll
        for (int j = 0; j < 4; ++j) {
            float2 cf = h2f(cc[j]);
            ob[j] = imv[j] + (-(cf.x + cf.y) + h2f(uu[j]).x + h2f(lt[j]).y);
        }
        *(float4*)&s[64][4 * tx] = make_float4(ob[0], ob[1], ob[2], ob[3]);
    }
    __syncthreads();

    float accd = 0.f, accn = 0.f;
    const float tw = TAU / w;
    #pragma unroll
    for (int i = 0; i < 4; ++i) {
        int ey = ry + 16 * i, gy = y0 + ey;
        float4 dn = *(float4*)&s[ey + 1][4 * tx];
        float rt_sh = __shfl_down(o[i][0], 1, 64);
        float rt = (tx == 15) ? s[ey][64] : rt_sh;
        float dnv[4] = {dn.x, dn.y, dn.z, dn.w};
        uint32_t pv[4];
        #pragma unroll
        for (int j = 0; j < 4; ++j) {
            float ov = o[i][j];
            float g0 = (gy < HH - 1) ? dnv[j] - ov : 0.f;
            float rn = (j < 3) ? o[i][j + 1] : rt;
            float g1 = (gx + j < WW - 1) ? rn - ov : 0.f;
            float ss2 = g0 * g0 + g1 * g1;
            float nrm = (ss2 > 0.f) ? sqrtf(ss2) : 0.f;
            accn += nrm;
            float dt = ov - im4[i][j];
            accd += dt * dt;
            float inv = 1.f / (1.f + tw * nrm);
            float2 cf = h2f(c[i][j]);
            pv[j] = f2h2((cf.x - TAU * g0) * inv, (cf.y - TAU * g1) * inv);
        }
        *(uint4*)(poutI + (size_t)gy * WW + gx) = make_uint4(pv[0], pv[1], pv[2], pv[3]);
    }
    block_reduce_store(accd, accn, &pd[im * 64 + bid], &pn[im * 64 + bid], tid);
}

// Deterministic per-image reduction + convergence bookkeeping.
__global__ void tv_reduce_fin(const float* __restrict__ weight,
                              float* __restrict__ sc,
                              const float* __restrict__ pd,
                              const float* __restrict__ pn, int it)
{
    const int im = blockIdx.x;
    int* done = (int*)(sc + 96);
    int* last_k = (int*)(sc + 120);
    if (it > 0 && done[im]) return;
    const int lane = threadIdx.x;
    float d = (it > 0) ? pd[im * 64 + lane] : 0.f;
    float n = pn[im * 64 + lane];
    for (int off = 32; off > 0; off >>= 1) {
        d += __shfl_down(d, off, 64);
        n += __shfl_down(n, off, 64);
    }
    if (lane == 0) {
        float w = weight[im / CCH];
        if (it == 0) {
            float E = w * n / NUMEL;
            sc[48 + im] = E;
            sc[72 + im] = E;
            done[im] = 0;
            last_k[im] = 0;
        } else {
            last_k[im] = it;
            float Et = (d + w * n) / NUMEL;
            if (fabsf(sc[48 + im] - Et) < TVEPS * sc[72 + im]) done[im] = 1;
            sc[48 + im] = Et;
        }
    }
}

// Epilogue: out = img(fp32) + div(pt input of each image's last executed step).
__global__ __launch_bounds__(256, 4) void tv_out(
    const float* __restrict__ img, float* __restrict__ out,
    const uint32_t* __restrict__ ptA, const uint32_t* __restrict__ ptB,
    const float* __restrict__ sc)
{
    const int im = blockIdx.z;
    const int* si = (const int*)sc;
    int k = si[96 + im] ? si[120 + im] : (NITER - 1);
    const uint32_t* p = ((((k - 1) & 1) == 0) ? ptA : ptB) + (size_t)im * HH * WW;
    const float* imgI = img + (size_t)im * HH * WW;
    float* outI = out + (size_t)im * HH * WW;
    const int x0 = blockIdx.x * 64, y0 = blockIdx.y * 64;
    const int tx = threadIdx.x & 15, ry = threadIdx.x >> 4;
    const int gx = x0 + 4 * tx;
    #pragma unroll
    for (int i = 0; i < 4; ++i) {
        int gy = y0 + ry + 16 * i;
        size_t off = (size_t)gy * WW + gx;
        uint4 cv = *(const uint4*)(p + off);
        uint4 uv = make_uint4(0u, 0u, 0u, 0u);
        if (gy > 0) uv = *(const uint4*)(p + off - WW);
        uint32_t lf = (gx > 0) ? p[off - 1] : 0u;
        float4 iv = *(const float4*)(imgI + off);
        uint32_t cc[4] = {cv.x, cv.y, cv.z, cv.w};
        uint32_t uu[4] = {uv.x, uv.y, uv.z, uv.w};
        uint32_t lt[4] = {lf, cv.x, cv.y, cv.z};
        float ivv[4] = {iv.x, iv.y, iv.z, iv.w};
        float r[4];
        #pragma unroll
        for (int j = 0; j < 4; ++j) {
            float2 cf = h2f(cc[j]);
            r[j] = ivv[j] + (-(cf.x + cf.y) + h2f(uu[j]).x + h2f(lt[j]).y);
        }
        *(float4*)(outI + off) = make_float4(r[0], r[1], r[2], r[3]);
    }
}

extern "C" void kernel_launch(void* const* d_in, const int* in_sizes, int n_in,
                              void* d_out, int out_size, void* d_ws, size_t ws_size,
                              hipStream_t stream)
{
    const float* img = (const float*)d_in[0];
    const float* weight = (const float*)d_in[1];
    float* out = (float*)d_out;
    float* sc = (float*)d_ws;
    float* pd = (float*)((char*)d_ws + 2048);
    float* pn = (float*)((char*)d_ws + 8192);
    __half* imgh = (__half*)((char*)d_ws + 16384);
    uint32_t* ptA = (uint32_t*)((char*)d_ws + 12599296);
    uint32_t* ptB = (uint32_t*)((char*)d_ws + 37765120);

    dim3 grid(8, 8, NIMG);
    dim3 block(256);

    tv_step0<<<grid, block, 0, stream>>>(img, weight, imgh, ptA, pd, pn);
    tv_reduce_fin<<<NIMG, 64, 0, stream>>>(weight, sc, pd, pn, 0);

    for (int it = 1; it < NITER; ++it) {
        uint32_t* pin  = (((it - 1) & 1) == 0) ? ptA : ptB;
        uint32_t* pout = ((it & 1) == 0) ? ptA : ptB;
        tv_stepN<<<grid, block, 0, stream>>>(imgh, weight, pin, pout, sc, pd, pn);
        if (it < NITER - 1)
            tv_reduce_fin<<<NIMG, 64, 0, stream>>>(weight, sc, pd, pn, it);
    }
    tv_out<<<grid, block, 0, stream>>>(img, out, ptA, ptB, sc);
}